// Round 1
// baseline (530.759 us; speedup 1.0000x reference)
//
#include <hip/hip_runtime.h>
#include <hip/hip_bf16.h>
#include <stdint.h>

// ---------------------------------------------------------------------------
// MultiHeadSeqAttention (Transformer-XL style sliding-window rel-pos attention)
// HID=1024, NHEADS=16, HEAD=64, MEM=512, LIM=2048, B=8
// logit(m,n) = q[m]·k[n] + q[m]·pe[:,n-m],  n-m in [0,2048)
// ---------------------------------------------------------------------------

typedef __attribute__((ext_vector_type(8))) __bf16 bfrag;   // MFMA A/B operand (8 bf16, 4 VGPR)
typedef __attribute__((ext_vector_type(4))) float f4;       // MFMA C/D (4 f32)

#define DEVFN static __device__ __forceinline__

DEVFN void glds16(const void* g, void* l) {
  __builtin_amdgcn_global_load_lds((const __attribute__((address_space(1))) void*)g,
                                   (__attribute__((address_space(3))) void*)l, 16, 0, 0);
}

// ------------------------- fp32 -> bf16 convert ----------------------------
__global__ __launch_bounds__(256) void convk(const float* __restrict__ s,
                                             __bf16* __restrict__ d, int n) {
  int i = (blockIdx.x * 256 + threadIdx.x) * 8;
  if (i >= n) return;
  f4 a = *(const f4*)(s + i);
  f4 b = *(const f4*)(s + i + 4);
  bfrag v;
  v[0] = (__bf16)a.x; v[1] = (__bf16)a.y; v[2] = (__bf16)a.z; v[3] = (__bf16)a.w;
  v[4] = (__bf16)b.x; v[5] = (__bf16)b.y; v[6] = (__bf16)b.z; v[7] = (__bf16)b.w;
  *(bfrag*)(d + i) = v;
}

// ---------------- transposed + zero-padded positional table ----------------
// peT[r][d], r in [0,2176): r = l + 64; zero for l<0 or l>=2048; else pe[d][l]
__global__ __launch_bounds__(256) void pek(const float* __restrict__ pe,
                                           __bf16* __restrict__ peT) {
  int i = blockIdx.x * 256 + threadIdx.x;   // grid covers 64*2048 + 128*64 exactly
  if (i < 64 * 2048) {
    int d = i >> 11, l = i & 2047;
    peT[(size_t)(l + 64) * 64 + d] = (__bf16)pe[i];
  } else {
    int zi = i - 64 * 2048;                 // [0, 8192)
    int row = zi >> 6, dd = zi & 63;
    int r = row < 64 ? row : (2112 + row - 64);
    peT[(size_t)r * 64 + dd] = (__bf16)0.f;
  }
}

// ----------------------------- GEMM C = A @ B^T ----------------------------
// A: [Mrows,1024] (fp32 or bf16, row-major, K contiguous)
// B: [1024,1024] bf16 row-major (W: out-feature rows, K contiguous)
// MODE 0: bf16 out, heads layout [b*16+h][s][d]   (q,k)
// MODE 1: bf16 out, transposed  [b*16+h][d][2560+s offset]   (v -> v^T)
// MODE 2: f32 out, row-major [Mrows][1024]        (final proj)
// 128x128 tile, BK=64, 4 waves (each 64x64), chunk-XOR swizzled LDS.
DEVFN void stageA_row(const float* ap, __bf16* lds, int arow, int ahalf) {
  const f4* p = (const f4*)ap;
#pragma unroll
  for (int q = 0; q < 4; ++q) {
    f4 a = p[2 * q], b = p[2 * q + 1];
    bfrag v;
    v[0] = (__bf16)a.x; v[1] = (__bf16)a.y; v[2] = (__bf16)a.z; v[3] = (__bf16)a.w;
    v[4] = (__bf16)b.x; v[5] = (__bf16)b.y; v[6] = (__bf16)b.z; v[7] = (__bf16)b.w;
    int ch = (4 * ahalf + q) ^ (arow & 7);
    *(bfrag*)&lds[arow * 64 + ch * 8] = v;
  }
}
DEVFN void stageA_row(const __bf16* ap, __bf16* lds, int arow, int ahalf) {
  const bfrag* p = (const bfrag*)ap;
#pragma unroll
  for (int q = 0; q < 4; ++q) {
    bfrag v = p[q];
    int ch = (4 * ahalf + q) ^ (arow & 7);
    *(bfrag*)&lds[arow * 64 + ch * 8] = v;
  }
}

template <int MODE, typename AT>
__global__ __launch_bounds__(256) void gemm_bt(const AT* __restrict__ A,
                                               const __bf16* __restrict__ B,
                                               void* __restrict__ Cout, int Sseq) {
  __shared__ alignas(16) __bf16 Alds[128 * 64];
  __shared__ alignas(16) __bf16 Blds[128 * 64];
  const int tid = threadIdx.x;
  const int lane = tid & 63, wv = tid >> 6;
  const int wr = wv >> 1, wc = wv & 1;
  const int g = lane >> 4, cl = lane & 15;
  const int arow = tid >> 1, ahalf = tid & 1;

  // XCD-aware swizzle: 8 consecutive blocks on one XCD share the same A row-tile
  int bx = blockIdx.x;
  int nb = gridDim.x;                       // multiple of 8
  int v = (bx & 7) * (nb >> 3) + (bx >> 3);
  const int r0 = (v >> 3) * 128;
  const int c0 = (v & 7) * 128;

  f4 acc[4][4] = {};

  for (int k0 = 0; k0 < 1024; k0 += 64) {
    __syncthreads();
    // stage B via global_load_lds, source pre-swizzled so swizzled-read works
#pragma unroll
    for (int i = 0; i < 4; ++i) {
      int slot = tid + 256 * i;
      int row = slot >> 3, ch = slot & 7;
      glds16(B + (size_t)(c0 + row) * 1024 + k0 + ((ch ^ (row & 7)) << 3),
             &Blds[slot << 3]);
    }
    // stage A (reg path, converts fp32->bf16 if needed), swizzled ds_write
    stageA_row(A + (size_t)(r0 + arow) * 1024 + k0 + ahalf * 32, Alds, arow, ahalf);
    __syncthreads();
#pragma unroll
    for (int kc = 0; kc < 2; ++kc) {
      bfrag af[4], bfv[4];
#pragma unroll
      for (int i = 0; i < 4; ++i) {
        int rA = 64 * wr + 16 * i + cl;
        af[i] = *(const bfrag*)&Alds[rA * 64 + (((g + 4 * kc) ^ (rA & 7)) << 3)];
        int rB = 64 * wc + 16 * i + cl;
        bfv[i] = *(const bfrag*)&Blds[rB * 64 + (((g + 4 * kc) ^ (rB & 7)) << 3)];
      }
#pragma unroll
      for (int am = 0; am < 4; ++am)
#pragma unroll
        for (int bn = 0; bn < 4; ++bn)
          acc[am][bn] =
              __builtin_amdgcn_mfma_f32_16x16x32_bf16(af[am], bfv[bn], acc[am][bn], 0, 0, 0);
    }
  }

  if constexpr (MODE == 2) {
    float* C = (float*)Cout;
#pragma unroll
    for (int am = 0; am < 4; ++am)
#pragma unroll
      for (int bn = 0; bn < 4; ++bn)
#pragma unroll
        for (int r = 0; r < 4; ++r) {
          int rg = r0 + 64 * wr + 16 * am + 4 * g + r;
          int jg = c0 + 64 * wc + 16 * bn + cl;
          C[(size_t)rg * 1024 + jg] = acc[am][bn][r];
        }
  } else {
    __bf16* C = (__bf16*)Cout;
    int b = r0 / Sseq;            // 128-row tile never crosses a batch boundary
    int sbase = r0 - b * Sseq;
#pragma unroll
    for (int am = 0; am < 4; ++am)
#pragma unroll
      for (int bn = 0; bn < 4; ++bn) {
        int jg = c0 + 64 * wc + 16 * bn + cl;
        int h = jg >> 6, d = jg & 63;
#pragma unroll
        for (int r = 0; r < 4; ++r) {
          int s = sbase + 64 * wr + 16 * am + 4 * g + r;
          size_t dst;
          if constexpr (MODE == 0)
            dst = ((size_t)(b * 16 + h) * Sseq + s) * 64 + d;
          else
            dst = ((size_t)(b * 16 + h) * 64 + d) * 2560 + s;
          C[dst] = (__bf16)acc[am][bn][r];
        }
      }
  }
}

// --------------------------- fused window attention ------------------------
// One block per (bh, 64-row query tile). 33 key tiles of 64.
// S[jm][jn] = (q·k + q·pe[:,l]) * scale, l = 64t + jn - jm, valid iff l in [0,2048).
// Positional band kept in a rolling 128-col LDS ring (64 new cols/iter).
#define SCL 0.18033688011112042f   // (1/8) * log2(e)

__global__ __launch_bounds__(256) void attnk(const __bf16* __restrict__ qws,
                                             const __bf16* __restrict__ kws,
                                             const __bf16* __restrict__ vtws,
                                             const __bf16* __restrict__ pews,
                                             __bf16* __restrict__ obuf) {
  __shared__ alignas(16) __bf16 Qs[64 * 64];
  __shared__ alignas(16) __bf16 Ks[64 * 64];
  __shared__ alignas(16) __bf16 Vs[64 * 64];    // V^T tile: [d][n]
  __shared__ alignas(16) __bf16 Ps[64 * 64];
  __shared__ alignas(16) __bf16 Pes[64 * 64];   // peT rows [64(t+1), 64(t+1)+64)
  __shared__ alignas(16) __bf16 Pbs[64 * 132];  // ring: Tpos[jm][l & 127] (+4 pad)

  int bx = blockIdx.x;
  int vv = (bx & 7) * 128 + (bx >> 3);          // XCD swizzle: one XCD = 16 bh groups
  int bh = vv >> 3, mt = vv & 7;
  int m0 = mt * 64;
  const __bf16* qb = qws + (size_t)bh * 512 * 64;
  const __bf16* kb = kws + (size_t)bh * 2560 * 64;
  const __bf16* vb = vtws + (size_t)bh * 64 * 2560;

  const int tid = threadIdx.x;
  const int lane = tid & 63, w = tid >> 6;
  const int g = lane >> 4, cl = lane & 15;

  // stage Q (contiguous 8KB), chunk-XOR pre-swizzled source
#pragma unroll
  for (int i = 0; i < 2; ++i) {
    int slot = tid + 256 * i;
    int row = slot >> 3, ch = slot & 7;
    glds16(qb + (size_t)(m0 + row) * 64 + ((ch ^ (row & 7)) << 3), &Qs[slot << 3]);
  }
  __syncthreads();
  // hoist all Q A-frags: qf_all[rb] covers rows 16rb..16rb+15 (Pb is col-split
  // across waves so every wave needs all rows; Sc uses qf_all[w]).
  bfrag qf_all[4][2];
#pragma unroll
  for (int rb = 0; rb < 4; ++rb) {
    int rq = 16 * rb + cl;
#pragma unroll
    for (int kc = 0; kc < 2; ++kc)
      qf_all[rb][kc] = *(const bfrag*)&Qs[rq * 64 + (((g + 4 * kc) ^ (rq & 7)) << 3)];
  }

  f4 o[4] = {};
  float mrow[4] = {-1e30f, -1e30f, -1e30f, -1e30f};
  float lrow[4] = {};

  for (int t = 0; t < 33; ++t) {
    int n0 = m0 + 64 * t;
    __syncthreads();
    // stage K tile [n][d], V^T tile [d][n], new PE rows
#pragma unroll
    for (int i = 0; i < 2; ++i) {
      int slot = tid + 256 * i;
      int row = slot >> 3, ch = slot & 7;
      glds16(kb + (size_t)(n0 + row) * 64 + ((ch ^ (row & 7)) << 3), &Ks[slot << 3]);
      glds16(vb + (size_t)row * 2560 + n0 + ((ch ^ (row & 7)) << 3), &Vs[slot << 3]);
      glds16(pews + (size_t)(64 * (t + 1) + row) * 64 + ((ch ^ (row & 7)) << 3),
             &Pes[slot << 3]);
    }
    __syncthreads();

    // content scores: wave w owns rows 16w..16w+15, all 64 cols
    f4 sc[4] = {};
#pragma unroll
    for (int kc = 0; kc < 2; ++kc)
#pragma unroll
      for (int cb = 0; cb < 4; ++cb) {
        int rk = 16 * cb + cl;
        bfrag kf = *(const bfrag*)&Ks[rk * 64 + (((g + 4 * kc) ^ (rk & 7)) << 3)];
        sc[cb] = __builtin_amdgcn_mfma_f32_16x16x32_bf16(qf_all[w][kc], kf, sc[cb], 0, 0, 0);
      }

    // positional band, new 64 cols (l = 64t + c2): col-split, wave w owns c2-block w
    f4 pbacc[4] = {};
#pragma unroll
    for (int kc = 0; kc < 2; ++kc) {
      int rp = 16 * w + cl;
      bfrag pf = *(const bfrag*)&Pes[rp * 64 + (((g + 4 * kc) ^ (rp & 7)) << 3)];
#pragma unroll
      for (int rb = 0; rb < 4; ++rb)
        pbacc[rb] = __builtin_amdgcn_mfma_f32_16x16x32_bf16(qf_all[rb][kc], pf, pbacc[rb], 0, 0, 0);
    }
    {
      int half = (t & 1) << 6;
      int c2 = 16 * w + cl;
#pragma unroll
      for (int rb = 0; rb < 4; ++rb)
#pragma unroll
        for (int r = 0; r < 4; ++r)
          Pbs[(16 * rb + 4 * g + r) * 132 + half + c2] = (__bf16)pbacc[rb][r];
    }
    __syncthreads();   // Pb written col-split, read row-split

    // online softmax (rows are wave-private; 16-lane shuffle reduce per row)
#pragma unroll
    for (int r = 0; r < 4; ++r) {
      int jm = 16 * w + 4 * g + r;
      float z[4];
#pragma unroll
      for (int cb = 0; cb < 4; ++cb) {
        int jn = 16 * cb + cl;
        int l = 64 * t + jn - jm;
        float pv = (float)Pbs[jm * 132 + (l & 127)];
        float zz = (sc[cb][r] + pv) * SCL;
        z[cb] = ((unsigned)l < 2048u) ? zz : -1e30f;
      }
      float tm = fmaxf(fmaxf(z[0], z[1]), fmaxf(z[2], z[3]));
#pragma unroll
      for (int off = 1; off < 16; off <<= 1) tm = fmaxf(tm, __shfl_xor(tm, off));
      float mnew = fmaxf(mrow[r], tm);
      float alpha = __builtin_amdgcn_exp2f(mrow[r] - mnew);
      mrow[r] = mnew;
      float ps = 0.f;
#pragma unroll
      for (int cb = 0; cb < 4; ++cb) {
        float p = __builtin_amdgcn_exp2f(z[cb] - mnew);
        ps += p;
        int jn = 16 * cb + cl;
        Ps[jm * 64 + (((jn >> 3) ^ (jm & 7)) << 3) + (jn & 7)] = (__bf16)p;
      }
#pragma unroll
      for (int off = 1; off < 16; off <<= 1) ps += __shfl_xor(ps, off);
      lrow[r] = lrow[r] * alpha + ps;
#pragma unroll
      for (int cb = 0; cb < 4; ++cb) o[cb][r] *= alpha;
    }

    // O += P @ V  (P rows wave-private; V^T gives k-contiguous B frags)
#pragma unroll
    for (int kc = 0; kc < 2; ++kc) {
      int rp2 = 16 * w + cl;
      bfrag pa = *(const bfrag*)&Ps[rp2 * 64 + (((g + 4 * kc) ^ (rp2 & 7)) << 3)];
#pragma unroll
      for (int cb = 0; cb < 4; ++cb) {
        int rv = 16 * cb + cl;
        bfrag vf = *(const bfrag*)&Vs[rv * 64 + (((g + 4 * kc) ^ (rv & 7)) << 3)];
        o[cb] = __builtin_amdgcn_mfma_f32_16x16x32_bf16(pa, vf, o[cb], 0, 0, 0);
      }
    }
  }

  // epilogue: normalize and write [b][m][h*64+d] bf16
  int b = bh >> 4, h = bh & 15;
#pragma unroll
  for (int cb = 0; cb < 4; ++cb)
#pragma unroll
    for (int r = 0; r < 4; ++r) {
      int m = m0 + 16 * w + 4 * g + r;
      int d = 16 * cb + cl;
      float val = o[cb][r] / lrow[r];
      obuf[((size_t)(b * 512 + m)) * 1024 + h * 64 + d] = (__bf16)val;
    }
}

// ---------------------------------------------------------------------------
extern "C" void kernel_launch(void* const* d_in, const int* in_sizes, int n_in,
                              void* d_out, int out_size, void* d_ws, size_t ws_size,
                              hipStream_t stream) {
  const float* query = (const float*)d_in[0];
  const float* key   = (const float*)d_in[1];
  const float* value = (const float*)d_in[2];
  const float* keype = (const float*)d_in[3];
  const float* Wq    = (const float*)d_in[4];
  const float* Wk    = (const float*)d_in[5];
  const float* Wv    = (const float*)d_in[6];
  const float* Wo    = (const float*)d_in[7];
  float* out = (float*)d_out;
  (void)in_sizes; (void)n_in; (void)out_size; (void)ws_size;

  char* ws = (char*)d_ws;
  size_t off = 0;
  auto alloc = [&](size_t bytes) {
    void* p = ws + off;
    off += (bytes + 255) & ~(size_t)255;
    return p;
  };
  __bf16* Wqb  = (__bf16*)alloc((size_t)1024 * 1024 * 2);
  __bf16* Wkb  = (__bf16*)alloc((size_t)1024 * 1024 * 2);
  __bf16* Wvb  = (__bf16*)alloc((size_t)1024 * 1024 * 2);
  __bf16* Wob  = (__bf16*)alloc((size_t)1024 * 1024 * 2);
  __bf16* peT  = (__bf16*)alloc((size_t)2176 * 64 * 2);
  __bf16* qws  = (__bf16*)alloc((size_t)128 * 512 * 64 * 2);
  __bf16* kws  = (__bf16*)alloc((size_t)128 * 2560 * 64 * 2);
  __bf16* vtws = (__bf16*)alloc((size_t)128 * 2560 * 64 * 2);
  __bf16* obuf = (__bf16*)alloc((size_t)4096 * 1024 * 2);
  // total ws use ~109 MB

  convk<<<512, 256, 0, stream>>>(Wq, Wqb, 1 << 20);
  convk<<<512, 256, 0, stream>>>(Wk, Wkb, 1 << 20);
  convk<<<512, 256, 0, stream>>>(Wv, Wvb, 1 << 20);
  convk<<<512, 256, 0, stream>>>(Wo, Wob, 1 << 20);
  pek<<<544, 256, 0, stream>>>(keype, peT);

  gemm_bt<0, float><<<256, 256, 0, stream>>>(query, Wqb, qws, 512);
  gemm_bt<0, float><<<1280, 256, 0, stream>>>(key, Wkb, kws, 2560);
  gemm_bt<1, float><<<1280, 256, 0, stream>>>(value, Wvb, vtws, 2560);

  attnk<<<1024, 256, 0, stream>>>(qws, kws, vtws, peT, obuf);

  gemm_bt<2, __bf16><<<256, 256, 0, stream>>>(obuf, Wob, out, 512);
}

// Round 2
// 450.563 us; speedup vs baseline: 1.1780x; 1.1780x over previous
//
#include <hip/hip_runtime.h>
#include <hip/hip_bf16.h>
#include <stdint.h>

// ---------------------------------------------------------------------------
// MultiHeadSeqAttention (Transformer-XL style sliding-window rel-pos attention)
// HID=1024, NHEADS=16, HEAD=64, MEM=512, LIM=2048, B=8
// logit(m,n) = q[m]·k[n] + q[m]·pe[:,n-m],  n-m in [0,2048)
// ---------------------------------------------------------------------------

typedef __attribute__((ext_vector_type(8))) __bf16 bfrag;   // MFMA A/B operand
typedef __attribute__((ext_vector_type(4))) float f4;       // MFMA C/D

#define DEVFN static __device__ __forceinline__

DEVFN void glds16(const void* g, void* l) {
  __builtin_amdgcn_global_load_lds((const __attribute__((address_space(1))) void*)g,
                                   (__attribute__((address_space(3))) void*)l, 16, 0, 0);
}

// ------------------ fp32 -> bf16 convert, 4 weights in one launch ----------
__global__ __launch_bounds__(256) void conv4(const float* __restrict__ a0, const float* __restrict__ a1,
                                             const float* __restrict__ a2, const float* __restrict__ a3,
                                             __bf16* __restrict__ d0, __bf16* __restrict__ d1,
                                             __bf16* __restrict__ d2, __bf16* __restrict__ d3) {
  int bx = blockIdx.x;
  int sel = bx >> 9;
  const float* s = sel == 0 ? a0 : sel == 1 ? a1 : sel == 2 ? a2 : a3;
  __bf16* d = sel == 0 ? d0 : sel == 1 ? d1 : sel == 2 ? d2 : d3;
  int i = ((bx & 511) * 256 + threadIdx.x) * 8;   // 512*256*8 = 1M exactly
  f4 a = *(const f4*)(s + i);
  f4 b = *(const f4*)(s + i + 4);
  bfrag v;
  v[0] = (__bf16)a.x; v[1] = (__bf16)a.y; v[2] = (__bf16)a.z; v[3] = (__bf16)a.w;
  v[4] = (__bf16)b.x; v[5] = (__bf16)b.y; v[6] = (__bf16)b.z; v[7] = (__bf16)b.w;
  *(bfrag*)(d + i) = v;
}

// ---------------- transposed + zero-padded positional table ----------------
// peT[r][d], r in [0,2176): r = l + 64; zero for l<0 or l>=2048; else pe[d][l]
__global__ __launch_bounds__(256) void pek(const float* __restrict__ pe,
                                           __bf16* __restrict__ peT) {
  int i = blockIdx.x * 256 + threadIdx.x;   // grid covers 64*2048 + 128*64 exactly
  if (i < 64 * 2048) {
    int d = i >> 11, l = i & 2047;
    peT[(size_t)(l + 64) * 64 + d] = (__bf16)pe[i];
  } else {
    int zi = i - 64 * 2048;                 // [0, 8192)
    int row = zi >> 6, dd = zi & 63;
    int r = row < 64 ? row : (2112 + row - 64);
    peT[(size_t)r * 64 + dd] = (__bf16)0.f;
  }
}

// ------------------------- shared GEMM staging helpers ---------------------
DEVFN void stageA_row(const float* ap, __bf16* lds, int arow, int ahalf) {
  const f4* p = (const f4*)ap;
#pragma unroll
  for (int q = 0; q < 4; ++q) {
    f4 a = p[2 * q], b = p[2 * q + 1];
    bfrag v;
    v[0] = (__bf16)a.x; v[1] = (__bf16)a.y; v[2] = (__bf16)a.z; v[3] = (__bf16)a.w;
    v[4] = (__bf16)b.x; v[5] = (__bf16)b.y; v[6] = (__bf16)b.z; v[7] = (__bf16)b.w;
    int ch = (4 * ahalf + q) ^ (arow & 7);
    *(bfrag*)&lds[arow * 64 + ch * 8] = v;
  }
}
DEVFN void stageA_row(const __bf16* ap, __bf16* lds, int arow, int ahalf) {
  const bfrag* p = (const bfrag*)ap;
#pragma unroll
  for (int q = 0; q < 4; ++q) {
    bfrag v = p[q];
    int ch = (4 * ahalf + q) ^ (arow & 7);
    *(bfrag*)&lds[arow * 64 + ch * 8] = v;
  }
}

// ---------------- fused q/k/v projection: C = A @ W^T, heads layout --------
// grid 2816: [0,256) q (S=512) | [256,1536) k (S=2560) | [1536,2816) v -> v^T
__global__ __launch_bounds__(256) void projk(const float* __restrict__ Aq, const float* __restrict__ Ak,
                                             const float* __restrict__ Av,
                                             const __bf16* __restrict__ Wqb, const __bf16* __restrict__ Wkb,
                                             const __bf16* __restrict__ Wvb,
                                             __bf16* __restrict__ qws, __bf16* __restrict__ kws,
                                             __bf16* __restrict__ vtws) {
  __shared__ alignas(16) __bf16 Alds[128 * 64];
  __shared__ alignas(16) __bf16 Blds[128 * 64];
  int bx = blockIdx.x;
  const float* A; const __bf16* B; __bf16* C; int nb, lb, rpb, trans;
  if (bx < 256)       { A = Aq; B = Wqb; C = qws;  lb = bx;        nb = 256;  rpb = 4;  trans = 0; }
  else if (bx < 1536) { A = Ak; B = Wkb; C = kws;  lb = bx - 256;  nb = 1280; rpb = 20; trans = 0; }
  else                { A = Av; B = Wvb; C = vtws; lb = bx - 1536; nb = 1280; rpb = 20; trans = 1; }

  const int tid = threadIdx.x;
  const int lane = tid & 63, wv = tid >> 6;
  const int wr = wv >> 1, wc = wv & 1;
  const int g = lane >> 4, cl = lane & 15;
  const int arow = tid >> 1, ahalf = tid & 1;

  int v = (lb & 7) * (nb >> 3) + (lb >> 3);   // XCD-aware swizzle (nb % 8 == 0)
  const int trow = v >> 3;
  const int r0 = trow * 128, c0 = (v & 7) * 128;

  f4 acc[4][4] = {};

  for (int k0 = 0; k0 < 1024; k0 += 64) {
    __syncthreads();
#pragma unroll
    for (int i = 0; i < 4; ++i) {
      int slot = tid + 256 * i;
      int row = slot >> 3, ch = slot & 7;
      glds16(B + (size_t)(c0 + row) * 1024 + k0 + ((ch ^ (row & 7)) << 3),
             &Blds[slot << 3]);
    }
    stageA_row(A + (size_t)(r0 + arow) * 1024 + k0 + ahalf * 32, Alds, arow, ahalf);
    __syncthreads();
#pragma unroll
    for (int kc = 0; kc < 2; ++kc) {
      bfrag af[4], bfv[4];
#pragma unroll
      for (int i = 0; i < 4; ++i) {
        int rA = 64 * wr + 16 * i + cl;
        af[i] = *(const bfrag*)&Alds[rA * 64 + (((g + 4 * kc) ^ (rA & 7)) << 3)];
        int rB = 64 * wc + 16 * i + cl;
        bfv[i] = *(const bfrag*)&Blds[rB * 64 + (((g + 4 * kc) ^ (rB & 7)) << 3)];
      }
#pragma unroll
      for (int am = 0; am < 4; ++am)
#pragma unroll
        for (int bn = 0; bn < 4; ++bn)
          acc[am][bn] =
              __builtin_amdgcn_mfma_f32_16x16x32_bf16(af[am], bfv[bn], acc[am][bn], 0, 0, 0);
    }
  }

  int Sseq = rpb << 7;
  int b = trow / rpb;                 // uniform scalar div, once
  int sbase = r0 - b * Sseq;
#pragma unroll
  for (int am = 0; am < 4; ++am)
#pragma unroll
    for (int bn = 0; bn < 4; ++bn) {
      int jg = c0 + 64 * wc + 16 * bn + cl;
      int h = jg >> 6, d = jg & 63;
#pragma unroll
      for (int r = 0; r < 4; ++r) {
        int s = sbase + 64 * wr + 16 * am + 4 * g + r;
        size_t dst = trans ? ((size_t)(b * 16 + h) * 64 + d) * 2560 + s
                           : ((size_t)(b * 16 + h) * Sseq + s) * 64 + d;
        C[dst] = (__bf16)acc[am][bn][r];
      }
    }
}

// -------------------------- output projection (f32 out) --------------------
__global__ __launch_bounds__(256) void gemm_out(const __bf16* __restrict__ A,
                                                const __bf16* __restrict__ B,
                                                float* __restrict__ C) {
  __shared__ alignas(16) __bf16 Alds[128 * 64];
  __shared__ alignas(16) __bf16 Blds[128 * 64];
  const int tid = threadIdx.x;
  const int lane = tid & 63, wv = tid >> 6;
  const int wr = wv >> 1, wc = wv & 1;
  const int g = lane >> 4, cl = lane & 15;
  const int arow = tid >> 1, ahalf = tid & 1;

  int bx = blockIdx.x;
  int v = (bx & 7) * 32 + (bx >> 3);          // 256 blocks
  const int r0 = (v >> 3) * 128, c0 = (v & 7) * 128;

  f4 acc[4][4] = {};
  for (int k0 = 0; k0 < 1024; k0 += 64) {
    __syncthreads();
#pragma unroll
    for (int i = 0; i < 4; ++i) {
      int slot = tid + 256 * i;
      int row = slot >> 3, ch = slot & 7;
      glds16(B + (size_t)(c0 + row) * 1024 + k0 + ((ch ^ (row & 7)) << 3),
             &Blds[slot << 3]);
    }
    stageA_row(A + (size_t)(r0 + arow) * 1024 + k0 + ahalf * 32, Alds, arow, ahalf);
    __syncthreads();
#pragma unroll
    for (int kc = 0; kc < 2; ++kc) {
      bfrag af[4], bfv[4];
#pragma unroll
      for (int i = 0; i < 4; ++i) {
        int rA = 64 * wr + 16 * i + cl;
        af[i] = *(const bfrag*)&Alds[rA * 64 + (((g + 4 * kc) ^ (rA & 7)) << 3)];
        int rB = 64 * wc + 16 * i + cl;
        bfv[i] = *(const bfrag*)&Blds[rB * 64 + (((g + 4 * kc) ^ (rB & 7)) << 3)];
      }
#pragma unroll
      for (int am = 0; am < 4; ++am)
#pragma unroll
        for (int bn = 0; bn < 4; ++bn)
          acc[am][bn] =
              __builtin_amdgcn_mfma_f32_16x16x32_bf16(af[am], bfv[bn], acc[am][bn], 0, 0, 0);
    }
  }
#pragma unroll
  for (int am = 0; am < 4; ++am)
#pragma unroll
    for (int bn = 0; bn < 4; ++bn)
#pragma unroll
      for (int r = 0; r < 4; ++r) {
        int rg = r0 + 64 * wr + 16 * am + 4 * g + r;
        int jg = c0 + 64 * wc + 16 * bn + cl;
        C[(size_t)rg * 1024 + jg] = acc[am][bn][r];
      }
}

// --------------------------- fused window attention ------------------------
// One block per (bh, 64-row query tile). 33 key tiles of 64.
// Fixed-max softmax: p = exp2((qk+qpe)*SCL - 20); normalization cancels the
// fixed bias exactly, per-lane partial sums reduced once in the epilogue.
// LDS 40960 B -> 4 blocks/CU (Qs aliases Vs, Pes aliases Ps).
#define SCL 0.18033688011112042f   // (1/8) * log2(e)
#define FMX 20.0f

__global__ __launch_bounds__(256) void attnk(const __bf16* __restrict__ qws,
                                             const __bf16* __restrict__ kws,
                                             const __bf16* __restrict__ vtws,
                                             const __bf16* __restrict__ pews,
                                             __bf16* __restrict__ obuf) {
  __shared__ alignas(16) __bf16 Ks[64 * 64];
  __shared__ alignas(16) __bf16 QVs[64 * 64];   // Q (prologue) then V^T tiles
  __shared__ alignas(16) __bf16 PPs[64 * 64];   // PE rows, then P (post-barrier)
  __shared__ alignas(16) __bf16 Pbs[64 * 128];  // pos ring: [jm][l & 127]

  int bx = blockIdx.x;
  int vv = (bx & 7) * 128 + (bx >> 3);          // XCD swizzle
  int bh = vv >> 3, mt = vv & 7;
  int m0 = mt * 64;
  const __bf16* qb = qws + (size_t)bh * 512 * 64;
  const __bf16* kb = kws + (size_t)bh * 2560 * 64;
  const __bf16* vb = vtws + (size_t)bh * 64 * 2560;

  const int tid = threadIdx.x;
  const int lane = tid & 63, w = tid >> 6;
  const int g = lane >> 4, cl = lane & 15;

  // stage Q (chunk-XOR pre-swizzled source), hoist all A-frags
#pragma unroll
  for (int i = 0; i < 2; ++i) {
    int slot = tid + 256 * i;
    int row = slot >> 3, ch = slot & 7;
    glds16(qb + (size_t)(m0 + row) * 64 + ((ch ^ (row & 7)) << 3), &QVs[slot << 3]);
  }
  __syncthreads();
  bfrag qf_all[4][2];
#pragma unroll
  for (int rb = 0; rb < 4; ++rb) {
    int rq = 16 * rb + cl;
#pragma unroll
    for (int kc = 0; kc < 2; ++kc)
      qf_all[rb][kc] = *(const bfrag*)&QVs[rq * 64 + (((g + 4 * kc) ^ (rq & 7)) << 3)];
  }

  f4 o[4] = {};
  float lsum[4] = {};

  for (int t = 0; t < 33; ++t) {
    int n0 = m0 + 64 * t;
    __syncthreads();
    // stage K tile [n][d], V^T tile [d][n] (into QVs), new PE rows (into PPs)
#pragma unroll
    for (int i = 0; i < 2; ++i) {
      int slot = tid + 256 * i;
      int row = slot >> 3, ch = slot & 7;
      glds16(kb + (size_t)(n0 + row) * 64 + ((ch ^ (row & 7)) << 3), &Ks[slot << 3]);
      glds16(vb + (size_t)row * 2560 + n0 + ((ch ^ (row & 7)) << 3), &QVs[slot << 3]);
      glds16(pews + (size_t)(64 * (t + 1) + row) * 64 + ((ch ^ (row & 7)) << 3),
             &PPs[slot << 3]);
    }
    __syncthreads();

    // content scores: wave w owns rows 16w..16w+15, all 64 cols
    f4 sc[4] = {};
    __builtin_amdgcn_s_setprio(1);
#pragma unroll
    for (int kc = 0; kc < 2; ++kc)
#pragma unroll
      for (int cb = 0; cb < 4; ++cb) {
        int rk = 16 * cb + cl;
        bfrag kf = *(const bfrag*)&Ks[rk * 64 + (((g + 4 * kc) ^ (rk & 7)) << 3)];
        sc[cb] = __builtin_amdgcn_mfma_f32_16x16x32_bf16(qf_all[w][kc], kf, sc[cb], 0, 0, 0);
      }
    // positional band, new 64 cols (l = 64t + c2): col-split across waves
    f4 pbacc[4] = {};
#pragma unroll
    for (int kc = 0; kc < 2; ++kc) {
      int rp = 16 * w + cl;
      bfrag pf = *(const bfrag*)&PPs[rp * 64 + (((g + 4 * kc) ^ (rp & 7)) << 3)];
#pragma unroll
      for (int rb = 0; rb < 4; ++rb)
        pbacc[rb] = __builtin_amdgcn_mfma_f32_16x16x32_bf16(qf_all[rb][kc], pf, pbacc[rb], 0, 0, 0);
    }
    __builtin_amdgcn_s_setprio(0);
    {
      int half = (t & 1) << 6;
      int c2 = 16 * w + cl;
#pragma unroll
      for (int rb = 0; rb < 4; ++rb)
#pragma unroll
        for (int r = 0; r < 4; ++r)
          Pbs[(16 * rb + 4 * g + r) * 128 + half + c2] = (__bf16)pbacc[rb][r];
    }
    __syncthreads();   // Pbs written col-split, read row-split; PPs reads done

    // fixed-max softmax: no shuffles, no rescale; P overwrites PE in PPs
    bool edge = (t == 0) || (t == 32);
#pragma unroll
    for (int r = 0; r < 4; ++r) {
      int jm = 16 * w + 4 * g + r;
#pragma unroll
      for (int cb = 0; cb < 4; ++cb) {
        int jn = 16 * cb + cl;
        int l = 64 * t + jn - jm;
        float pv = (float)Pbs[jm * 128 + (l & 127)];
        float ex = fmaf(sc[cb][r] + pv, SCL, -FMX);
        if (edge) ex = ((unsigned)l < 2048u) ? ex : -1e30f;
        float p = __builtin_amdgcn_exp2f(ex);
        lsum[r] += p;
        PPs[jm * 64 + (((jn >> 3) ^ (jm & 7)) << 3) + (jn & 7)] = (__bf16)p;
      }
    }

    // O += P @ V  (P rows wave-private -> no barrier; V^T gives k-contig frags)
    __builtin_amdgcn_s_setprio(1);
#pragma unroll
    for (int kc = 0; kc < 2; ++kc) {
      int rp2 = 16 * w + cl;
      bfrag pa = *(const bfrag*)&PPs[rp2 * 64 + (((g + 4 * kc) ^ (rp2 & 7)) << 3)];
#pragma unroll
      for (int cb = 0; cb < 4; ++cb) {
        int rv = 16 * cb + cl;
        bfrag vf = *(const bfrag*)&QVs[rv * 64 + (((g + 4 * kc) ^ (rv & 7)) << 3)];
        o[cb] = __builtin_amdgcn_mfma_f32_16x16x32_bf16(pa, vf, o[cb], 0, 0, 0);
      }
    }
    __builtin_amdgcn_s_setprio(0);
  }

  // epilogue: reduce lsum over the 16 cl-lanes, normalize, write bf16
#pragma unroll
  for (int r = 0; r < 4; ++r)
#pragma unroll
    for (int off = 1; off < 16; off <<= 1) lsum[r] += __shfl_xor(lsum[r], off);

  int b = bh >> 4, h = bh & 15;
#pragma unroll
  for (int cb = 0; cb < 4; ++cb)
#pragma unroll
    for (int r = 0; r < 4; ++r) {
      int m = m0 + 16 * w + 4 * g + r;
      int d = 16 * cb + cl;
      obuf[((size_t)(b * 512 + m)) * 1024 + h * 64 + d] = (__bf16)(o[cb][r] / lsum[r]);
    }
}

// ---------------------------------------------------------------------------
extern "C" void kernel_launch(void* const* d_in, const int* in_sizes, int n_in,
                              void* d_out, int out_size, void* d_ws, size_t ws_size,
                              hipStream_t stream) {
  const float* query = (const float*)d_in[0];
  const float* key   = (const float*)d_in[1];
  const float* value = (const float*)d_in[2];
  const float* keype = (const float*)d_in[3];
  const float* Wq    = (const float*)d_in[4];
  const float* Wk    = (const float*)d_in[5];
  const float* Wv    = (const float*)d_in[6];
  const float* Wo    = (const float*)d_in[7];
  float* out = (float*)d_out;
  (void)in_sizes; (void)n_in; (void)out_size; (void)ws_size;

  char* ws = (char*)d_ws;
  size_t off = 0;
  auto alloc = [&](size_t bytes) {
    void* p = ws + off;
    off += (bytes + 255) & ~(size_t)255;
    return p;
  };
  __bf16* Wqb  = (__bf16*)alloc((size_t)1024 * 1024 * 2);
  __bf16* Wkb  = (__bf16*)alloc((size_t)1024 * 1024 * 2);
  __bf16* Wvb  = (__bf16*)alloc((size_t)1024 * 1024 * 2);
  __bf16* Wob  = (__bf16*)alloc((size_t)1024 * 1024 * 2);
  __bf16* peT  = (__bf16*)alloc((size_t)2176 * 64 * 2);
  __bf16* qws  = (__bf16*)alloc((size_t)128 * 512 * 64 * 2);
  __bf16* kws  = (__bf16*)alloc((size_t)128 * 2560 * 64 * 2);
  __bf16* vtws = (__bf16*)alloc((size_t)128 * 2560 * 64 * 2);
  __bf16* obuf = (__bf16*)alloc((size_t)4096 * 1024 * 2);

  conv4<<<2048, 256, 0, stream>>>(Wq, Wk, Wv, Wo, Wqb, Wkb, Wvb, Wob);
  pek<<<544, 256, 0, stream>>>(keype, peT);
  projk<<<2816, 256, 0, stream>>>(query, key, value, Wqb, Wkb, Wvb, qws, kws, vtws);
  attnk<<<1024, 256, 0, stream>>>(qws, kws, vtws, peT, obuf);
  gemm_out<<<256, 256, 0, stream>>>(obuf, Wob, out);
}

// Round 3
// 395.007 us; speedup vs baseline: 1.3437x; 1.1406x over previous
//
#include <hip/hip_runtime.h>
#include <hip/hip_bf16.h>
#include <stdint.h>

// ---------------------------------------------------------------------------
// MultiHeadSeqAttention (Transformer-XL style sliding-window rel-pos attention)
// HID=1024, NHEADS=16, HEAD=64, MEM=512, LIM=2048, B=8
// logit(m,n) = q[m]·k[n] + q[m]·pe[:,n-m],  n-m in [0,2048)
// ---------------------------------------------------------------------------

typedef __attribute__((ext_vector_type(8))) __bf16 bfrag;   // MFMA A/B operand
typedef __attribute__((ext_vector_type(4))) float f4;       // MFMA C/D

#define DEVFN static __device__ __forceinline__

DEVFN void glds16(const void* g, void* l) {
  __builtin_amdgcn_global_load_lds((const __attribute__((address_space(1))) void*)g,
                                   (__attribute__((address_space(3))) void*)l, 16, 0, 0);
}

DEVFN bfrag cvt8(const float* p) {
  f4 a = *(const f4*)p;
  f4 b = *(const f4*)(p + 4);
  bfrag v;
  v[0] = (__bf16)a.x; v[1] = (__bf16)a.y; v[2] = (__bf16)a.z; v[3] = (__bf16)a.w;
  v[4] = (__bf16)b.x; v[5] = (__bf16)b.y; v[6] = (__bf16)b.z; v[7] = (__bf16)b.w;
  return v;
}

// ------------------ fp32 -> bf16 convert, 4 weights in one launch ----------
__global__ __launch_bounds__(256) void conv4(const float* __restrict__ a0, const float* __restrict__ a1,
                                             const float* __restrict__ a2, const float* __restrict__ a3,
                                             __bf16* __restrict__ d0, __bf16* __restrict__ d1,
                                             __bf16* __restrict__ d2, __bf16* __restrict__ d3) {
  int bx = blockIdx.x;
  int sel = bx >> 9;
  const float* s = sel == 0 ? a0 : sel == 1 ? a1 : sel == 2 ? a2 : a3;
  __bf16* d = sel == 0 ? d0 : sel == 1 ? d1 : sel == 2 ? d2 : d3;
  int i = ((bx & 511) * 256 + (int)threadIdx.x) * 8;   // 512*256*8 = 1M exactly
  *(bfrag*)(d + i) = cvt8(s + i);
}

// ------------------ fp32 -> bf16 convert for q/k/v inputs ------------------
// grid 22528: q 2048 blocks | k 10240 | v 10240; 2048 elems/block
__global__ __launch_bounds__(256) void convin(const float* __restrict__ q, const float* __restrict__ k,
                                              const float* __restrict__ v,
                                              __bf16* __restrict__ qd, __bf16* __restrict__ kd,
                                              __bf16* __restrict__ vd) {
  int bx = blockIdx.x;
  const float* s; __bf16* d; int lb;
  if (bx < 2048)       { s = q; d = qd; lb = bx; }
  else if (bx < 12288) { s = k; d = kd; lb = bx - 2048; }
  else                 { s = v; d = vd; lb = bx - 12288; }
  int i = (lb * 256 + (int)threadIdx.x) * 8;
  *(bfrag*)(d + i) = cvt8(s + i);
}

// ---------------- transposed + zero-padded positional table ----------------
// peT[r][d], r in [0,2176): r = l + 64; zero for l<0 or l>=2048; else pe[d][l]
__global__ __launch_bounds__(256) void pek(const float* __restrict__ pe,
                                           __bf16* __restrict__ peT) {
  int i = blockIdx.x * 256 + threadIdx.x;   // grid covers 64*2048 + 128*64 exactly
  if (i < 64 * 2048) {
    int d = i >> 11, l = i & 2047;
    peT[(size_t)(l + 64) * 64 + d] = (__bf16)pe[i];
  } else {
    int zi = i - 64 * 2048;                 // [0, 8192)
    int row = zi >> 6, dd = zi & 63;
    int r = row < 64 ? row : (2112 + row - 64);
    peT[(size_t)r * 64 + dd] = (__bf16)0.f;
  }
}

// ------------------------- fp32 A reg-staging (fallback) -------------------
DEVFN void stageA_row(const float* ap, __bf16* lds, int arow, int ahalf) {
  const f4* p = (const f4*)ap;
#pragma unroll
  for (int q = 0; q < 4; ++q) {
    f4 a = p[2 * q], b = p[2 * q + 1];
    bfrag v;
    v[0] = (__bf16)a.x; v[1] = (__bf16)a.y; v[2] = (__bf16)a.z; v[3] = (__bf16)a.w;
    v[4] = (__bf16)b.x; v[5] = (__bf16)b.y; v[6] = (__bf16)b.z; v[7] = (__bf16)b.w;
    int ch = (4 * ahalf + q) ^ (arow & 7);
    *(bfrag*)&lds[arow * 64 + ch * 8] = v;
  }
}

// ---------------- fused q/k/v projection: C = A @ W^T, heads layout --------
// grid 2816: [0,256) q (S=512) | [256,1536) k (S=2560) | [1536,2816) v -> v^T
// AMODE 1: bf16 A via global_load_lds (fast); AMODE 0: fp32 A via reg staging.
template <int AMODE, typename AT>
__global__ __launch_bounds__(256) void projk(const AT* __restrict__ Aq, const AT* __restrict__ Ak,
                                             const AT* __restrict__ Av,
                                             const __bf16* __restrict__ Wqb, const __bf16* __restrict__ Wkb,
                                             const __bf16* __restrict__ Wvb,
                                             __bf16* __restrict__ qws, __bf16* __restrict__ kws,
                                             __bf16* __restrict__ vtws) {
  __shared__ alignas(16) __bf16 Alds[128 * 64];
  __shared__ alignas(16) __bf16 Blds[128 * 64];
  int bx = blockIdx.x;
  const AT* A; const __bf16* B; __bf16* C; int nb, lb, rpb, trans;
  if (bx < 256)       { A = Aq; B = Wqb; C = qws;  lb = bx;        nb = 256;  rpb = 4;  trans = 0; }
  else if (bx < 1536) { A = Ak; B = Wkb; C = kws;  lb = bx - 256;  nb = 1280; rpb = 20; trans = 0; }
  else                { A = Av; B = Wvb; C = vtws; lb = bx - 1536; nb = 1280; rpb = 20; trans = 1; }

  const int tid = threadIdx.x;
  const int lane = tid & 63, wv = tid >> 6;
  const int wr = wv >> 1, wc = wv & 1;
  const int g = lane >> 4, cl = lane & 15;

  int v = (lb & 7) * (nb >> 3) + (lb >> 3);   // XCD-aware swizzle (nb % 8 == 0)
  const int trow = v >> 3;
  const int r0 = trow * 128, c0 = (v & 7) * 128;

  f4 acc[4][4] = {};

  for (int k0 = 0; k0 < 1024; k0 += 64) {
    __syncthreads();
#pragma unroll
    for (int i = 0; i < 4; ++i) {
      int slot = tid + 256 * i;
      int row = slot >> 3, ch = slot & 7;
      glds16(B + (size_t)(c0 + row) * 1024 + k0 + ((ch ^ (row & 7)) << 3),
             &Blds[slot << 3]);
      if constexpr (AMODE == 1)
        glds16(A + (size_t)(r0 + row) * 1024 + k0 + ((ch ^ (row & 7)) << 3),
               &Alds[slot << 3]);
    }
    if constexpr (AMODE == 0)
      stageA_row(A + (size_t)(r0 + (tid >> 1)) * 1024 + k0 + (tid & 1) * 32,
                 Alds, tid >> 1, tid & 1);
    __syncthreads();
#pragma unroll
    for (int kc = 0; kc < 2; ++kc) {
      bfrag af[4], bfv[4];
#pragma unroll
      for (int i = 0; i < 4; ++i) {
        int rA = 64 * wr + 16 * i + cl;
        af[i] = *(const bfrag*)&Alds[rA * 64 + (((g + 4 * kc) ^ (rA & 7)) << 3)];
        int rB = 64 * wc + 16 * i + cl;
        bfv[i] = *(const bfrag*)&Blds[rB * 64 + (((g + 4 * kc) ^ (rB & 7)) << 3)];
      }
#pragma unroll
      for (int am = 0; am < 4; ++am)
#pragma unroll
        for (int bn = 0; bn < 4; ++bn)
          acc[am][bn] =
              __builtin_amdgcn_mfma_f32_16x16x32_bf16(af[am], bfv[bn], acc[am][bn], 0, 0, 0);
    }
  }

  int Sseq = rpb << 7;
  int b = trow / rpb;                 // uniform scalar div, once
  int sbase = r0 - b * Sseq;
#pragma unroll
  for (int am = 0; am < 4; ++am)
#pragma unroll
    for (int bn = 0; bn < 4; ++bn) {
      int jg = c0 + 64 * wc + 16 * bn + cl;
      int h = jg >> 6, d = jg & 63;
#pragma unroll
      for (int r = 0; r < 4; ++r) {
        int s = sbase + 64 * wr + 16 * am + 4 * g + r;
        size_t dst = trans ? ((size_t)(b * 16 + h) * 64 + d) * 2560 + s
                           : ((size_t)(b * 16 + h) * Sseq + s) * 64 + d;
        C[dst] = (__bf16)acc[am][bn][r];
      }
    }
}

// -------------------------- output projection (f32 out) --------------------
__global__ __launch_bounds__(256) void gemm_out(const __bf16* __restrict__ A,
                                                const __bf16* __restrict__ B,
                                                float* __restrict__ C) {
  __shared__ alignas(16) __bf16 Alds[128 * 64];
  __shared__ alignas(16) __bf16 Blds[128 * 64];
  const int tid = threadIdx.x;
  const int lane = tid & 63, wv = tid >> 6;
  const int wr = wv >> 1, wc = wv & 1;
  const int g = lane >> 4, cl = lane & 15;

  int bx = blockIdx.x;
  int v = (bx & 7) * 32 + (bx >> 3);          // 256 blocks
  const int r0 = (v >> 3) * 128, c0 = (v & 7) * 128;

  f4 acc[4][4] = {};
  for (int k0 = 0; k0 < 1024; k0 += 64) {
    __syncthreads();
#pragma unroll
    for (int i = 0; i < 4; ++i) {
      int slot = tid + 256 * i;
      int row = slot >> 3, ch = slot & 7;
      glds16(B + (size_t)(c0 + row) * 1024 + k0 + ((ch ^ (row & 7)) << 3),
             &Blds[slot << 3]);
      glds16(A + (size_t)(r0 + row) * 1024 + k0 + ((ch ^ (row & 7)) << 3),
             &Alds[slot << 3]);
    }
    __syncthreads();
#pragma unroll
    for (int kc = 0; kc < 2; ++kc) {
      bfrag af[4], bfv[4];
#pragma unroll
      for (int i = 0; i < 4; ++i) {
        int rA = 64 * wr + 16 * i + cl;
        af[i] = *(const bfrag*)&Alds[rA * 64 + (((g + 4 * kc) ^ (rA & 7)) << 3)];
        int rB = 64 * wc + 16 * i + cl;
        bfv[i] = *(const bfrag*)&Blds[rB * 64 + (((g + 4 * kc) ^ (rB & 7)) << 3)];
      }
#pragma unroll
      for (int am = 0; am < 4; ++am)
#pragma unroll
        for (int bn = 0; bn < 4; ++bn)
          acc[am][bn] =
              __builtin_amdgcn_mfma_f32_16x16x32_bf16(af[am], bfv[bn], acc[am][bn], 0, 0, 0);
    }
  }
#pragma unroll
  for (int am = 0; am < 4; ++am)
#pragma unroll
    for (int bn = 0; bn < 4; ++bn)
#pragma unroll
      for (int r = 0; r < 4; ++r) {
        int rg = r0 + 64 * wr + 16 * am + 4 * g + r;
        int jg = c0 + 64 * wc + 16 * bn + cl;
        C[(size_t)rg * 1024 + jg] = acc[am][bn][r];
      }
}

// --------------------------- fused window attention ------------------------
// One block per (bh, 64-row query tile). 33 key tiles of 64.
// Fixed-max softmax: p = exp2((qk+qpe)*SCL - 20); normalization cancels the
// fixed bias exactly, per-lane partial sums reduced once in the epilogue.
// LDS 40960 B -> 4 blocks/CU (Qs aliases Vs, Pes aliases Ps).
#define SCL 0.18033688011112042f   // (1/8) * log2(e)
#define FMX 20.0f

__global__ __launch_bounds__(256) void attnk(const __bf16* __restrict__ qws,
                                             const __bf16* __restrict__ kws,
                                             const __bf16* __restrict__ vtws,
                                             const __bf16* __restrict__ pews,
                                             __bf16* __restrict__ obuf) {
  __shared__ alignas(16) __bf16 Ks[64 * 64];
  __shared__ alignas(16) __bf16 QVs[64 * 64];   // Q (prologue) then V^T tiles
  __shared__ alignas(16) __bf16 PPs[64 * 64];   // PE rows, then P (post-barrier)
  __shared__ alignas(16) __bf16 Pbs[64 * 128];  // pos ring: [jm][l & 127]

  int bx = blockIdx.x;
  int vv = (bx & 7) * 128 + (bx >> 3);          // XCD swizzle
  int bh = vv >> 3, mt = vv & 7;
  int m0 = mt * 64;
  const __bf16* qb = qws + (size_t)bh * 512 * 64;
  const __bf16* kb = kws + (size_t)bh * 2560 * 64;
  const __bf16* vb = vtws + (size_t)bh * 64 * 2560;

  const int tid = threadIdx.x;
  const int lane = tid & 63, w = tid >> 6;
  const int g = lane >> 4, cl = lane & 15;

  // stage Q (chunk-XOR pre-swizzled source), hoist all A-frags
#pragma unroll
  for (int i = 0; i < 2; ++i) {
    int slot = tid + 256 * i;
    int row = slot >> 3, ch = slot & 7;
    glds16(qb + (size_t)(m0 + row) * 64 + ((ch ^ (row & 7)) << 3), &QVs[slot << 3]);
  }
  __syncthreads();
  bfrag qf_all[4][2];
#pragma unroll
  for (int rb = 0; rb < 4; ++rb) {
    int rq = 16 * rb + cl;
#pragma unroll
    for (int kc = 0; kc < 2; ++kc)
      qf_all[rb][kc] = *(const bfrag*)&QVs[rq * 64 + (((g + 4 * kc) ^ (rq & 7)) << 3)];
  }

  f4 o[4] = {};
  float lsum[4] = {};

  for (int t = 0; t < 33; ++t) {
    int n0 = m0 + 64 * t;
    __syncthreads();
    // stage K tile [n][d], V^T tile [d][n] (into QVs), new PE rows (into PPs)
#pragma unroll
    for (int i = 0; i < 2; ++i) {
      int slot = tid + 256 * i;
      int row = slot >> 3, ch = slot & 7;
      glds16(kb + (size_t)(n0 + row) * 64 + ((ch ^ (row & 7)) << 3), &Ks[slot << 3]);
      glds16(vb + (size_t)row * 2560 + n0 + ((ch ^ (row & 7)) << 3), &QVs[slot << 3]);
      glds16(pews + (size_t)(64 * (t + 1) + row) * 64 + ((ch ^ (row & 7)) << 3),
             &PPs[slot << 3]);
    }
    __syncthreads();

    // content scores: wave w owns rows 16w..16w+15, all 64 cols
    f4 sc[4] = {};
    __builtin_amdgcn_s_setprio(1);
#pragma unroll
    for (int kc = 0; kc < 2; ++kc)
#pragma unroll
      for (int cb = 0; cb < 4; ++cb) {
        int rk = 16 * cb + cl;
        bfrag kf = *(const bfrag*)&Ks[rk * 64 + (((g + 4 * kc) ^ (rk & 7)) << 3)];
        sc[cb] = __builtin_amdgcn_mfma_f32_16x16x32_bf16(qf_all[w][kc], kf, sc[cb], 0, 0, 0);
      }
    // positional band, new 64 cols (l = 64t + c2): col-split across waves
    f4 pbacc[4] = {};
#pragma unroll
    for (int kc = 0; kc < 2; ++kc) {
      int rp = 16 * w + cl;
      bfrag pf = *(const bfrag*)&PPs[rp * 64 + (((g + 4 * kc) ^ (rp & 7)) << 3)];
#pragma unroll
      for (int rb = 0; rb < 4; ++rb)
        pbacc[rb] = __builtin_amdgcn_mfma_f32_16x16x32_bf16(qf_all[rb][kc], pf, pbacc[rb], 0, 0, 0);
    }
    __builtin_amdgcn_s_setprio(0);
    {
      int half = (t & 1) << 6;
      int c2 = 16 * w + cl;
#pragma unroll
      for (int rb = 0; rb < 4; ++rb)
#pragma unroll
        for (int r = 0; r < 4; ++r)
          Pbs[(16 * rb + 4 * g + r) * 128 + half + c2] = (__bf16)pbacc[rb][r];
    }
    __syncthreads();   // Pbs written col-split, read row-split; PPs reads done

    // fixed-max softmax: no shuffles, no rescale; P overwrites PE in PPs
    bool edge = (t == 0) || (t == 32);
#pragma unroll
    for (int r = 0; r < 4; ++r) {
      int jm = 16 * w + 4 * g + r;
#pragma unroll
      for (int cb = 0; cb < 4; ++cb) {
        int jn = 16 * cb + cl;
        int l = 64 * t + jn - jm;
        float pv = (float)Pbs[jm * 128 + (l & 127)];
        float ex = fmaf(sc[cb][r] + pv, SCL, -FMX);
        if (edge) ex = ((unsigned)l < 2048u) ? ex : -1e30f;
        float p = __builtin_amdgcn_exp2f(ex);
        lsum[r] += p;
        PPs[jm * 64 + (((jn >> 3) ^ (jm & 7)) << 3) + (jn & 7)] = (__bf16)p;
      }
    }

    // O += P @ V  (P rows wave-private -> no barrier; V^T gives k-contig frags)
    __builtin_amdgcn_s_setprio(1);
#pragma unroll
    for (int kc = 0; kc < 2; ++kc) {
      int rp2 = 16 * w + cl;
      bfrag pa = *(const bfrag*)&PPs[rp2 * 64 + (((g + 4 * kc) ^ (rp2 & 7)) << 3)];
#pragma unroll
      for (int cb = 0; cb < 4; ++cb) {
        int rv = 16 * cb + cl;
        bfrag vf = *(const bfrag*)&QVs[rv * 64 + (((g + 4 * kc) ^ (rv & 7)) << 3)];
        o[cb] = __builtin_amdgcn_mfma_f32_16x16x32_bf16(pa, vf, o[cb], 0, 0, 0);
      }
    }
    __builtin_amdgcn_s_setprio(0);
  }

  // epilogue: reduce lsum over the 16 cl-lanes, normalize, write bf16
#pragma unroll
  for (int r = 0; r < 4; ++r)
#pragma unroll
    for (int off = 1; off < 16; off <<= 1) lsum[r] += __shfl_xor(lsum[r], off);

  int b = bh >> 4, h = bh & 15;
#pragma unroll
  for (int cb = 0; cb < 4; ++cb)
#pragma unroll
    for (int r = 0; r < 4; ++r) {
      int m = m0 + 16 * w + 4 * g + r;
      int d = 16 * cb + cl;
      obuf[((size_t)(b * 512 + m)) * 1024 + h * 64 + d] = (__bf16)(o[cb][r] / lsum[r]);
    }
}

// ---------------------------------------------------------------------------
extern "C" void kernel_launch(void* const* d_in, const int* in_sizes, int n_in,
                              void* d_out, int out_size, void* d_ws, size_t ws_size,
                              hipStream_t stream) {
  const float* query = (const float*)d_in[0];
  const float* key   = (const float*)d_in[1];
  const float* value = (const float*)d_in[2];
  const float* keype = (const float*)d_in[3];
  const float* Wq    = (const float*)d_in[4];
  const float* Wk    = (const float*)d_in[5];
  const float* Wv    = (const float*)d_in[6];
  const float* Wo    = (const float*)d_in[7];
  float* out = (float*)d_out;
  (void)in_sizes; (void)n_in; (void)out_size;

  char* ws = (char*)d_ws;
  size_t off = 0;
  auto alloc = [&](size_t bytes) {
    void* p = ws + off;
    off += (bytes + 255) & ~(size_t)255;
    return p;
  };
  __bf16* Wqb  = (__bf16*)alloc((size_t)1024 * 1024 * 2);
  __bf16* Wkb  = (__bf16*)alloc((size_t)1024 * 1024 * 2);
  __bf16* Wvb  = (__bf16*)alloc((size_t)1024 * 1024 * 2);
  __bf16* Wob  = (__bf16*)alloc((size_t)1024 * 1024 * 2);
  __bf16* peT  = (__bf16*)alloc((size_t)2176 * 64 * 2);
  __bf16* qws  = (__bf16*)alloc((size_t)128 * 512 * 64 * 2);
  __bf16* kws  = (__bf16*)alloc((size_t)128 * 2560 * 64 * 2);
  __bf16* vtws = (__bf16*)alloc((size_t)128 * 2560 * 64 * 2);

  // big-ws path: bf16 copies of q/k/v inputs (+92 MB); obuf aliases qbf
  // (disjoint live ranges: qbf dead after projk, obuf born at attnk).
  const size_t NEED = (size_t)194 * 1024 * 1024;
  bool big = ws_size >= NEED;

  conv4<<<2048, 256, 0, stream>>>(Wq, Wk, Wv, Wo, Wqb, Wkb, Wvb, Wob);
  pek<<<544, 256, 0, stream>>>(keype, peT);

  __bf16* obuf;
  if (big) {
    __bf16* qbf = (__bf16*)alloc((size_t)8 * 512 * 1024 * 2);
    __bf16* kbf = (__bf16*)alloc((size_t)8 * 2560 * 1024 * 2);
    __bf16* vbf = (__bf16*)alloc((size_t)8 * 2560 * 1024 * 2);
    obuf = qbf;
    convin<<<22528, 256, 0, stream>>>(query, key, value, qbf, kbf, vbf);
    projk<1, __bf16><<<2816, 256, 0, stream>>>(qbf, kbf, vbf, Wqb, Wkb, Wvb,
                                               qws, kws, vtws);
  } else {
    obuf = (__bf16*)alloc((size_t)4096 * 1024 * 2);
    projk<0, float><<<2816, 256, 0, stream>>>(query, key, value, Wqb, Wkb, Wvb,
                                              qws, kws, vtws);
  }

  attnk<<<1024, 256, 0, stream>>>(qws, kws, vtws, peT, obuf);
  gemm_out<<<256, 256, 0, stream>>>(obuf, Wob, out);
}